// Round 18
// baseline (190.707 us; speedup 1.0000x reference)
//
#include <hip/hip_runtime.h>
#include <math.h>

#define BB 32768
#define CC 8
#define HH 128
#define RR 16
#define GG 384
#define TT 32
#define NT32 (BB / TT + CC - 1)   // 1031
#define REPEAT 16                 // PROFILING ROUND: in-kernel repeat so the main
                                  // dispatch tops rocprof's table. M = dur/16.

// ---- workspace layout (bytes) ----
#define R16_OFF   256                              // ushort rows16[CC][BB]  512 KB
#define MFRAG_OFF (R16_OFF + CC * BB * 2)          // bf16 Mfrag, fragment-major, 768 KB
#define COMB_OFF  (MFRAG_OFF + CC * 24 * 4 * 512 * 2)
#define WS_NEEDED (COMB_OFF + CC * 4 * HH * 4)

typedef short short8 __attribute__((ext_vector_type(8)));
typedef float f32x4  __attribute__((ext_vector_type(4)));

__device__ __forceinline__ unsigned short f2bf(float f) {
    unsigned int u = __float_as_uint(f);
    return (unsigned short)((u + 0x7fffu + ((u >> 16) & 1u)) >> 16);
}
__device__ __forceinline__ float bf2f(unsigned short b) {
    return __uint_as_float(((unsigned int)b) << 16);
}
__device__ __forceinline__ float sigmoidf_fast(float v) { return 1.f / (1.f + __expf(-v)); }
__device__ __forceinline__ float tanhf_fast(float v)    { return 2.f / (1.f + __expf(-2.f * v)) - 1.f; }

// ---------------- pass 0: fragment-major M + comb + zero cnt ----------------
// Mfrag element id: [c][ct(24)][ks(4)][lane(64)][e(8)] (bf16)
//   col = ct*16 + (lane&15)  (col = gate*128 + i, ct = gate*8 + w)
//   j   = ks*32 + (lane>>4)*8 + e
//   val = sum_r U[c][col][r] * V[c][j][r]
// A wave's B-frag load for (c,ct,ks) is then ONE contiguous 1KB burst.
__global__ __launch_bounds__(256) void prep_kernel(
    const float* __restrict__ U, const float* __restrict__ V,
    const float* __restrict__ bih, const float* __restrict__ bhh,
    unsigned short* __restrict__ Mfrag, float* __restrict__ comb,
    int* __restrict__ cnt)
{
    const int id = blockIdx.x * 256 + threadIdx.x;
    if (blockIdx.x == 0 && threadIdx.x < CC) cnt[threadIdx.x] = 0;

    const int NM = CC * 24 * 4 * 512;   // 393216
    if (id < NM) {
        const int c    = id / 49152;
        const int rem  = id - c * 49152;
        const int ct   = rem >> 11;           // /2048
        const int rem2 = rem & 2047;
        const int ks   = rem2 >> 9;           // /512
        const int l8   = rem2 & 511;
        const int l    = l8 >> 3, e = l8 & 7;
        const int col  = ct * 16 + (l & 15);
        const int j    = ks * 32 + (l >> 4) * 8 + e;
        const float* Up = U + ((size_t)c * GG + col) * RR;
        const float* Vp = V + ((size_t)c * HH + j) * RR;
        float s = 0.f;
        #pragma unroll
        for (int r = 0; r < RR; ++r) s += Up[r] * Vp[r];
        Mfrag[id] = f2bf(s);
    } else if (id < NM + CC * 4 * HH) {
        const int e = id - NM;             // 0..4095
        const int c = e >> 9, s = e & 511;
        const int gate = s >> 7, i = s & 127;
        float v;
        if      (gate == 0) v = bih[c * GG + i]       + bhh[c * GG + i];
        else if (gate == 1) v = bih[c * GG + 128 + i] + bhh[c * GG + 128 + i];
        else if (gate == 2) v = bhh[c * GG + 256 + i];
        else                v = bih[c * GG + 256 + i];
        comb[e] = v;
    }
}

// ---------------- pass 1: bucket rows by condition (ushort) ----------------
__global__ __launch_bounds__(256) void bucket_kernel(
    const float* __restrict__ x, int* __restrict__ cnt,
    unsigned short* __restrict__ rows16)
{
    __shared__ int lcnt[CC];
    __shared__ int lbase[CC];
    const int tid = threadIdx.x;
    const int b = blockIdx.x * 256 + tid;

    if (tid < CC) lcnt[tid] = 0;
    __syncthreads();

    const float4 x0 = *(const float4*)(x + (size_t)b * CC);
    const float4 x1 = *(const float4*)(x + (size_t)b * CC + 4);
    int c = 0;
    if      (x0.x != 0.f) c = 0;
    else if (x0.y != 0.f) c = 1;
    else if (x0.z != 0.f) c = 2;
    else if (x0.w != 0.f) c = 3;
    else if (x1.x != 0.f) c = 4;
    else if (x1.y != 0.f) c = 5;
    else if (x1.z != 0.f) c = 6;
    else if (x1.w != 0.f) c = 7;

    const int mypos = atomicAdd(&lcnt[c], 1);
    __syncthreads();
    if (tid < CC) lbase[tid] = atomicAdd(&cnt[tid], lcnt[tid]);
    __syncthreads();
    rows16[c * BB + lbase[c] + mypos] = (unsigned short)b;
}

// ---------------- pass 2: TT=32, 512-thread, full-width, coalesced B-frags ----------------
// wave w owns output features i in [w*16, w*16+16), ALL 3 gates (gate-tiles w, 8+w, 16+w).
// Each B-frag load = contiguous 1KB wave burst from Mfrag.
__global__ __launch_bounds__(512) void gru_m_kernel(
    const float* __restrict__ x, const float* __restrict__ h,
    const unsigned short* __restrict__ Mfrag, const float* __restrict__ comb_g,
    const unsigned short* __restrict__ rows16, const int* __restrict__ cnt,
    float* __restrict__ out)
{
    // tile descriptor
    int ncs[CC], tcs[CC];
    #pragma unroll
    for (int q = 0; q < CC; ++q) { ncs[q] = cnt[q]; tcs[q] = (ncs[q] + TT - 1) / TT; }
    const int tile = blockIdx.x;
    int c = -1, start = 0, nc = 0, base = 0;
    #pragma unroll
    for (int q = 0; q < CC; ++q) {
        if (c < 0 && tile < base + tcs[q]) { c = q; start = (tile - base) * TT; nc = ncs[q]; }
        base += tcs[q];
    }
    if (c < 0) return;

    __shared__ __align__(16) unsigned short hs[TT][HH + 8];  // 8.7 KB
    __shared__ float comb_s[512];                             // 2 KB
    __shared__ int   rloc[TT];
    __shared__ float wloc[TT];

    const int tid  = threadIdx.x;
    const int w    = tid >> 6;     // wave 0..7
    const int lane = tid & 63;
    const int r16  = lane & 15;
    const int hi   = lane >> 4;

    for (int rep = 0; rep < REPEAT; ++rep) {
        // stage h rows: 16 threads/row, 8 floats each
        {
            const int row = tid >> 4, seg = tid & 15;
            const int idx = start + row;
            const int b = (idx < nc) ? (int)rows16[c * BB + idx] : -1;
            short8 hv = {0, 0, 0, 0, 0, 0, 0, 0};
            if (b >= 0) {
                const float4 h0 = *(const float4*)(h + (size_t)b * HH + seg * 8);
                const float4 h1 = *(const float4*)(h + (size_t)b * HH + seg * 8 + 4);
                hv[0] = (short)f2bf(h0.x); hv[1] = (short)f2bf(h0.y);
                hv[2] = (short)f2bf(h0.z); hv[3] = (short)f2bf(h0.w);
                hv[4] = (short)f2bf(h1.x); hv[5] = (short)f2bf(h1.y);
                hv[6] = (short)f2bf(h1.z); hv[7] = (short)f2bf(h1.w);
            }
            *(short8*)&hs[row][seg * 8] = hv;
        }
        if (tid < TT) {
            const int idx = start + tid;
            const int b = (idx < nc) ? (int)rows16[c * BB + idx] : -1;
            rloc[tid] = b;
            wloc[tid] = (b >= 0) ? x[(size_t)b * CC + c] : 0.f;
        }
        comb_s[tid] = comb_g[c * 512 + tid];
        __syncthreads();

        // A-fragments (2 M-tiles)
        short8 az[2][4];
        #pragma unroll
        for (int mt = 0; mt < 2; ++mt)
            #pragma unroll
            for (int ks = 0; ks < 4; ++ks)
                az[mt][ks] = *(const short8*)&hs[mt * 16 + r16][ks * 32 + hi * 8];

        // GEMM: 3 gate-tiles (ct = g*8 + w), B-frags are 1KB contiguous bursts
        f32x4 acc[3][2];
        #pragma unroll
        for (int g = 0; g < 3; ++g)
            #pragma unroll
            for (int mt = 0; mt < 2; ++mt)
                acc[g][mt] = (f32x4){0.f, 0.f, 0.f, 0.f};

        const unsigned short* Mc = Mfrag + (size_t)c * 49152;
        #pragma unroll
        for (int g = 0; g < 3; ++g) {
            const int ct = g * 8 + w;
            #pragma unroll
            for (int ks = 0; ks < 4; ++ks) {
                const short8 bf = *(const short8*)(Mc + ((size_t)ct * 4 + ks) * 512 + lane * 8);
                acc[g][0] = __builtin_amdgcn_mfma_f32_16x16x32_bf16(az[0][ks], bf, acc[g][0], 0, 0, 0);
                acc[g][1] = __builtin_amdgcn_mfma_f32_16x16x32_bf16(az[1][ks], bf, acc[g][1], 0, 0, 0);
            }
        }

        // epilogue: i = w*16 + r16
        const int i = w * 16 + r16;
        const float cbr  = comb_s[i];
        const float cbz  = comb_s[128 + i];
        const float cbnh = comb_s[256 + i];
        const float cbni = comb_s[384 + i];
        #pragma unroll
        for (int mt = 0; mt < 2; ++mt) {
            #pragma unroll
            for (int q = 0; q < 4; ++q) {
                const int row = mt * 16 + 4 * hi + q;
                const int b   = rloc[row];
                const float wv = wloc[row];
                const float rg = sigmoidf_fast(acc[0][mt][q] + wv * cbr);
                const float zg = sigmoidf_fast(acc[1][mt][q] + wv * cbz);
                const float ng = tanhf_fast(wv * cbni + rg * (acc[2][mt][q] + wv * cbnh));
                const float hv = bf2f(hs[row][i]);
                if (b >= 0)
                    out[(size_t)b * HH + i] = (1.f - zg) * ng + zg * hv;
            }
        }
        __syncthreads();   // protect hs before next rep restages
    }
}

// ---------------- fallback if ws too small ----------------
__global__ __launch_bounds__(128) void gru_cell_naive(
    const float* __restrict__ x, const float* __restrict__ h,
    const float* __restrict__ U, const float* __restrict__ V,
    const float* __restrict__ bias_ih, const float* __restrict__ bias_hh,
    float* __restrict__ out)
{
    const int b = blockIdx.x;
    const int i = threadIdx.x;
    __shared__ float hsn[HH];
    __shared__ float xsn[CC];
    __shared__ float vhn[RR];
    const float h_i = h[b * HH + i];
    hsn[i] = h_i;
    if (i < CC) xsn[i] = x[b * CC + i];
    __syncthreads();
    float g_r = 0.f, g_z = 0.f, g_n = 0.f;
    float bi_r = 0.f, bi_z = 0.f, bi_n = 0.f;
    float bh_r = 0.f, bh_z = 0.f, bh_n = 0.f;
    for (int c = 0; c < CC; ++c) {
        const float w = xsn[c];
        if (w != 0.f) {
            if (i < RR) {
                const float* Vp = V + c * HH * RR + i;
                float a0 = 0.f;
                for (int j = 0; j < HH; ++j) a0 += Vp[j * RR] * hsn[j];
                vhn[i] = a0;
            }
            __syncthreads();
            const float* Up = U + c * 3 * HH * RR;
            float s_r = 0.f, s_z = 0.f, s_n = 0.f;
            for (int r = 0; r < RR; ++r) s_r += Up[i * RR + r] * vhn[r];
            for (int r = 0; r < RR; ++r) s_z += Up[(HH + i) * RR + r] * vhn[r];
            for (int r = 0; r < RR; ++r) s_n += Up[(2 * HH + i) * RR + r] * vhn[r];
            g_r += w * s_r; g_z += w * s_z; g_n += w * s_n;
            bi_r += w * bias_ih[c * GG + i];
            bi_z += w * bias_ih[c * GG + HH + i];
            bi_n += w * bias_ih[c * GG + 2 * HH + i];
            bh_r += w * bias_hh[c * GG + i];
            bh_z += w * bias_hh[c * GG + HH + i];
            bh_n += w * bias_hh[c * GG + 2 * HH + i];
            __syncthreads();
        }
    }
    const float rg = 1.f / (1.f + __expf(-(bi_r + g_r + bh_r)));
    const float zg = 1.f / (1.f + __expf(-(bi_z + g_z + bh_z)));
    const float ng = tanhf(bi_n + rg * (g_n + bh_n));
    out[b * HH + i] = (1.f - zg) * ng + zg * h_i;
}

extern "C" void kernel_launch(void* const* d_in, const int* in_sizes, int n_in,
                              void* d_out, int out_size, void* d_ws, size_t ws_size,
                              hipStream_t stream) {
    const float* x       = (const float*)d_in[0];
    const float* h       = (const float*)d_in[1];
    const float* U       = (const float*)d_in[2];
    const float* V       = (const float*)d_in[3];
    const float* bias_ih = (const float*)d_in[4];
    const float* bias_hh = (const float*)d_in[5];
    float* out = (float*)d_out;

    if (ws_size < (size_t)WS_NEEDED) {
        gru_cell_naive<<<BB, HH, 0, stream>>>(x, h, U, V, bias_ih, bias_hh, out);
        return;
    }

    int*            cnt    = (int*)d_ws;
    unsigned short* rows16 = (unsigned short*)((char*)d_ws + R16_OFF);
    unsigned short* Mfrag  = (unsigned short*)((char*)d_ws + MFRAG_OFF);
    float*          comb   = (float*)((char*)d_ws + COMB_OFF);

    const int prep_elems = CC * 24 * 4 * 512 + CC * 4 * HH;   // 397312
    prep_kernel<<<(prep_elems + 255) / 256, 256, 0, stream>>>(
        U, V, bias_ih, bias_hh, Mfrag, comb, cnt);
    bucket_kernel<<<BB / 256, 256, 0, stream>>>(x, cnt, rows16);
    gru_m_kernel<<<NT32, 512, 0, stream>>>(x, h, Mfrag, comb, rows16, cnt, out);
}

// Round 19
// 30.958 us; speedup vs baseline: 6.1602x; 6.1602x over previous
//
#include <hip/hip_runtime.h>
#include <hip/hip_bf16.h>
#include <math.h>

#define BB 32768
#define CC 8
#define HH 128
#define RR 16
#define GG 384
#define TT 32
#define NT32 (BB / TT + CC - 1)   // 1031

// ---- workspace layout (bytes) ----
#define R16_OFF   256                              // ushort rows16[CC][BB]  512 KB
#define MFRAG_OFF (R16_OFF + CC * BB * 2)          // bf16 Mfrag, fragment-major, 768 KB
#define COMB_OFF  (MFRAG_OFF + CC * 24 * 4 * 512 * 2)
#define WS_NEEDED (COMB_OFF + CC * 4 * HH * 4)

typedef short short8 __attribute__((ext_vector_type(8)));
typedef float f32x4  __attribute__((ext_vector_type(4)));

__device__ __forceinline__ unsigned short f2bf(float f) {   // prep only (cold path)
    unsigned int u = __float_as_uint(f);
    return (unsigned short)((u + 0x7fffu + ((u >> 16) & 1u)) >> 16);
}
__device__ __forceinline__ unsigned short f2bfn(float f) {  // hot path: native cvt
    __hip_bfloat16 h = __float2bfloat16(f);
    unsigned short u;
    __builtin_memcpy(&u, &h, 2);
    return u;
}
__device__ __forceinline__ float bf2f(unsigned short b) {
    return __uint_as_float(((unsigned int)b) << 16);
}
__device__ __forceinline__ float sigmoidf_fast(float v) { return 1.f / (1.f + __expf(-v)); }
__device__ __forceinline__ float tanhf_fast(float v)    { return 2.f / (1.f + __expf(-2.f * v)) - 1.f; }

// ---------------- pass 0: fragment-major M + comb + zero cnt ----------------
// Mfrag element id: [c][ct(24)][ks(4)][lane(64)][e(8)] (bf16)
//   col = ct*16 + (lane&15); j = ks*32 + (lane>>4)*8 + e; val = sum_r U[col][r]*V[j][r]
__global__ __launch_bounds__(256) void prep_kernel(
    const float* __restrict__ U, const float* __restrict__ V,
    const float* __restrict__ bih, const float* __restrict__ bhh,
    unsigned short* __restrict__ Mfrag, float* __restrict__ comb,
    int* __restrict__ cnt)
{
    const int id = blockIdx.x * 256 + threadIdx.x;
    if (blockIdx.x == 0 && threadIdx.x < CC) cnt[threadIdx.x] = 0;

    const int NM = CC * 24 * 4 * 512;   // 393216
    if (id < NM) {
        const int c    = id / 49152;
        const int rem  = id - c * 49152;
        const int ct   = rem >> 11;
        const int rem2 = rem & 2047;
        const int ks   = rem2 >> 9;
        const int l8   = rem2 & 511;
        const int l    = l8 >> 3, e = l8 & 7;
        const int col  = ct * 16 + (l & 15);
        const int j    = ks * 32 + (l >> 4) * 8 + e;
        const float* Up = U + ((size_t)c * GG + col) * RR;
        const float* Vp = V + ((size_t)c * HH + j) * RR;
        float s = 0.f;
        #pragma unroll
        for (int r = 0; r < RR; ++r) s += Up[r] * Vp[r];
        Mfrag[id] = f2bf(s);
    } else if (id < NM + CC * 4 * HH) {
        const int e = id - NM;
        const int c = e >> 9, s = e & 511;
        const int gate = s >> 7, i = s & 127;
        float v;
        if      (gate == 0) v = bih[c * GG + i]       + bhh[c * GG + i];
        else if (gate == 1) v = bih[c * GG + 128 + i] + bhh[c * GG + 128 + i];
        else if (gate == 2) v = bhh[c * GG + 256 + i];
        else                v = bih[c * GG + 256 + i];
        comb[e] = v;
    }
}

// ---------------- pass 1: bucket rows by condition (ushort) ----------------
__global__ __launch_bounds__(256) void bucket_kernel(
    const float* __restrict__ x, int* __restrict__ cnt,
    unsigned short* __restrict__ rows16)
{
    __shared__ int lcnt[CC];
    __shared__ int lbase[CC];
    const int tid = threadIdx.x;
    const int b = blockIdx.x * 256 + tid;

    if (tid < CC) lcnt[tid] = 0;
    __syncthreads();

    const float4 x0 = *(const float4*)(x + (size_t)b * CC);
    const float4 x1 = *(const float4*)(x + (size_t)b * CC + 4);
    int c = 0;
    if      (x0.x != 0.f) c = 0;
    else if (x0.y != 0.f) c = 1;
    else if (x0.z != 0.f) c = 2;
    else if (x0.w != 0.f) c = 3;
    else if (x1.x != 0.f) c = 4;
    else if (x1.y != 0.f) c = 5;
    else if (x1.z != 0.f) c = 6;
    else if (x1.w != 0.f) c = 7;

    const int mypos = atomicAdd(&lcnt[c], 1);
    __syncthreads();
    if (tid < CC) lbase[tid] = atomicAdd(&cnt[tid], lcnt[tid]);
    __syncthreads();
    rows16[c * BB + lbase[c] + mypos] = (unsigned short)b;
}

// ---------------- pass 2: TT=32, 512-thread, fragment-major coalesced B ----------------
__global__ __launch_bounds__(512) void gru_m_kernel(
    const float* __restrict__ x, const float* __restrict__ h,
    const unsigned short* __restrict__ Mfrag, const float* __restrict__ comb_g,
    const unsigned short* __restrict__ rows16, const int* __restrict__ cnt,
    float* __restrict__ out)
{
    // tile descriptor
    int ncs[CC], tcs[CC];
    #pragma unroll
    for (int q = 0; q < CC; ++q) { ncs[q] = cnt[q]; tcs[q] = (ncs[q] + TT - 1) / TT; }
    const int tile = blockIdx.x;
    int c = -1, start = 0, nc = 0, base = 0;
    #pragma unroll
    for (int q = 0; q < CC; ++q) {
        if (c < 0 && tile < base + tcs[q]) { c = q; start = (tile - base) * TT; nc = ncs[q]; }
        base += tcs[q];
    }
    if (c < 0) return;

    __shared__ __align__(16) unsigned short hs[TT][HH + 8];  // 8.7 KB
    __shared__ float comb_s[512];                             // 2 KB
    __shared__ int   oloc[TT];                                // b*HH, or <0 sentinel
    __shared__ float wloc[TT];

    const int tid  = threadIdx.x;
    const int w    = tid >> 6;     // wave 0..7
    const int lane = tid & 63;
    const int r16  = lane & 15;
    const int hi   = lane >> 4;

    // stage h rows: 16 threads/row, 8 floats each; native cvt (1-2 inst per pair)
    {
        const int row = tid >> 4, seg = tid & 15;
        const int idx = start + row;
        const int b = (idx < nc) ? (int)rows16[c * BB + idx] : -1;
        short8 hv = {0, 0, 0, 0, 0, 0, 0, 0};
        if (b >= 0) {
            const float4 h0 = *(const float4*)(h + (size_t)b * HH + seg * 8);
            const float4 h1 = *(const float4*)(h + (size_t)b * HH + seg * 8 + 4);
            hv[0] = (short)f2bfn(h0.x); hv[1] = (short)f2bfn(h0.y);
            hv[2] = (short)f2bfn(h0.z); hv[3] = (short)f2bfn(h0.w);
            hv[4] = (short)f2bfn(h1.x); hv[5] = (short)f2bfn(h1.y);
            hv[6] = (short)f2bfn(h1.z); hv[7] = (short)f2bfn(h1.w);
        }
        *(short8*)&hs[row][seg * 8] = hv;
    }
    if (tid < TT) {
        const int idx = start + tid;
        const int b = (idx < nc) ? (int)rows16[c * BB + idx] : -1;
        oloc[tid] = (b >= 0) ? b * HH : -1;
        wloc[tid] = (b >= 0) ? x[(size_t)b * CC + c] : 0.f;
    }
    comb_s[tid] = comb_g[c * 512 + tid];
    __syncthreads();

    // A-fragments (2 M-tiles)
    short8 az[2][4];
    #pragma unroll
    for (int mt = 0; mt < 2; ++mt)
        #pragma unroll
        for (int ks = 0; ks < 4; ++ks)
            az[mt][ks] = *(const short8*)&hs[mt * 16 + r16][ks * 32 + hi * 8];

    // GEMM: 3 gate-tiles (ct = g*8 + w); each B-frag = contiguous 1KB wave burst
    f32x4 acc[3][2];
    #pragma unroll
    for (int g = 0; g < 3; ++g)
        #pragma unroll
        for (int mt = 0; mt < 2; ++mt)
            acc[g][mt] = (f32x4){0.f, 0.f, 0.f, 0.f};

    const unsigned short* Mc = Mfrag + (size_t)c * 49152;
    #pragma unroll
    for (int g = 0; g < 3; ++g) {
        const int ct = g * 8 + w;
        #pragma unroll
        for (int ks = 0; ks < 4; ++ks) {
            const short8 bf = *(const short8*)(Mc + ((size_t)ct * 4 + ks) * 512 + lane * 8);
            acc[g][0] = __builtin_amdgcn_mfma_f32_16x16x32_bf16(az[0][ks], bf, acc[g][0], 0, 0, 0);
            acc[g][1] = __builtin_amdgcn_mfma_f32_16x16x32_bf16(az[1][ks], bf, acc[g][1], 0, 0, 0);
        }
    }

    // epilogue: i = w*16 + r16
    const int i = w * 16 + r16;
    const float cbr  = comb_s[i];
    const float cbz  = comb_s[128 + i];
    const float cbnh = comb_s[256 + i];
    const float cbni = comb_s[384 + i];
    #pragma unroll
    for (int mt = 0; mt < 2; ++mt) {
        #pragma unroll
        for (int q = 0; q < 4; ++q) {
            const int row = mt * 16 + 4 * hi + q;
            const int ob  = oloc[row];
            const float wv = wloc[row];
            const float rg = sigmoidf_fast(fmaf(wv, cbr, acc[0][mt][q]));
            const float zg = sigmoidf_fast(fmaf(wv, cbz, acc[1][mt][q]));
            const float ng = tanhf_fast(fmaf(rg, fmaf(wv, cbnh, acc[2][mt][q]), wv * cbni));
            const float hv = bf2f(hs[row][i]);
            if (ob >= 0)
                out[(size_t)(ob + i)] = fmaf(zg, hv - ng, ng);
        }
    }
}

// ---------------- fallback if ws too small ----------------
__global__ __launch_bounds__(128) void gru_cell_naive(
    const float* __restrict__ x, const float* __restrict__ h,
    const float* __restrict__ U, const float* __restrict__ V,
    const float* __restrict__ bias_ih, const float* __restrict__ bias_hh,
    float* __restrict__ out)
{
    const int b = blockIdx.x;
    const int i = threadIdx.x;
    __shared__ float hsn[HH];
    __shared__ float xsn[CC];
    __shared__ float vhn[RR];
    const float h_i = h[b * HH + i];
    hsn[i] = h_i;
    if (i < CC) xsn[i] = x[b * CC + i];
    __syncthreads();
    float g_r = 0.f, g_z = 0.f, g_n = 0.f;
    float bi_r = 0.f, bi_z = 0.f, bi_n = 0.f;
    float bh_r = 0.f, bh_z = 0.f, bh_n = 0.f;
    for (int c = 0; c < CC; ++c) {
        const float w = xsn[c];
        if (w != 0.f) {
            if (i < RR) {
                const float* Vp = V + c * HH * RR + i;
                float a0 = 0.f;
                for (int j = 0; j < HH; ++j) a0 += Vp[j * RR] * hsn[j];
                vhn[i] = a0;
            }
            __syncthreads();
            const float* Up = U + c * 3 * HH * RR;
            float s_r = 0.f, s_z = 0.f, s_n = 0.f;
            for (int r = 0; r < RR; ++r) s_r += Up[i * RR + r] * vhn[r];
            for (int r = 0; r < RR; ++r) s_z += Up[(HH + i) * RR + r] * vhn[r];
            for (int r = 0; r < RR; ++r) s_n += Up[(2 * HH + i) * RR + r] * vhn[r];
            g_r += w * s_r; g_z += w * s_z; g_n += w * s_n;
            bi_r += w * bias_ih[c * GG + i];
            bi_z += w * bias_ih[c * GG + HH + i];
            bi_n += w * bias_ih[c * GG + 2 * HH + i];
            bh_r += w * bias_hh[c * GG + i];
            bh_z += w * bias_hh[c * GG + HH + i];
            bh_n += w * bias_hh[c * GG + 2 * HH + i];
            __syncthreads();
        }
    }
    const float rg = 1.f / (1.f + __expf(-(bi_r + g_r + bh_r)));
    const float zg = 1.f / (1.f + __expf(-(bi_z + g_z + bh_z)));
    const float ng = tanhf(bi_n + rg * (g_n + bh_n));
    out[b * HH + i] = (1.f - zg) * ng + zg * h_i;
}

extern "C" void kernel_launch(void* const* d_in, const int* in_sizes, int n_in,
                              void* d_out, int out_size, void* d_ws, size_t ws_size,
                              hipStream_t stream) {
    const float* x       = (const float*)d_in[0];
    const float* h       = (const float*)d_in[1];
    const float* U       = (const float*)d_in[2];
    const float* V       = (const float*)d_in[3];
    const float* bias_ih = (const float*)d_in[4];
    const float* bias_hh = (const float*)d_in[5];
    float* out = (float*)d_out;

    if (ws_size < (size_t)WS_NEEDED) {
        gru_cell_naive<<<BB, HH, 0, stream>>>(x, h, U, V, bias_ih, bias_hh, out);
        return;
    }

    int*            cnt    = (int*)d_ws;
    unsigned short* rows16 = (unsigned short*)((char*)d_ws + R16_OFF);
    unsigned short* Mfrag  = (unsigned short*)((char*)d_ws + MFRAG_OFF);
    float*          comb   = (float*)((char*)d_ws + COMB_OFF);

    const int prep_elems = CC * 24 * 4 * 512 + CC * 4 * HH;   // 397312
    prep_kernel<<<(prep_elems + 255) / 256, 256, 0, stream>>>(
        U, V, bias_ih, bias_hh, Mfrag, comb, cnt);
    bucket_kernel<<<BB / 256, 256, 0, stream>>>(x, cnt, rows16);
    gru_m_kernel<<<NT32, 512, 0, stream>>>(x, h, Mfrag, comb, rows16, cnt, out);
}